// Round 20
// baseline (475.109 us; speedup 1.0000x reference)
//
#include <hip/hip_runtime.h>

#define LSEQ 4096
#define BSZ 2
#define DMODEL 1024
#define DINNER 2048
#define NHEADS 32
#define HEADDIM 64
#define DSTATE 128
#define CHUNK 256
#define NCHUNK 16
#define CONVDIM 2304
#define DINPROJ 4384
#define NPAD 4480
#define BL (BSZ*LSEQ)

typedef unsigned short u16;
typedef unsigned int u32;
typedef u16 u16x4 __attribute__((ext_vector_type(4)));
typedef u16 u16x8 __attribute__((ext_vector_type(8)));
typedef __bf16 bf16x8 __attribute__((ext_vector_type(8)));
typedef float f32x4 __attribute__((ext_vector_type(4)));

__device__ __forceinline__ u16 f2bf(float f){
  union { float f; u32 u; } v; v.f = f;
  u32 r = v.u + 0x7fffu + ((v.u >> 16) & 1u);
  return (u16)(r >> 16);
}
__device__ __forceinline__ float bf2f(u16 h){
  union { u32 u; float f; } v; v.u = ((u32)h) << 16;
  return v.f;
}
__device__ __forceinline__ u32 pack2(float a, float b){
  return (u32)f2bf(a) | ((u32)f2bf(b) << 16);
}
__device__ __forceinline__ f32x4 mfma16(bf16x8 a, bf16x8 b, f32x4 c){
  return __builtin_amdgcn_mfma_f32_16x16x32_bf16(a, b, c, 0, 0, 0);
}
// async global->LDS, 16B per lane; LDS dest is wave-uniform base + lane*16
__device__ __forceinline__ void gload16(const void* g, void* l){
  __builtin_amdgcn_global_load_lds((const __attribute__((address_space(1))) void*)g,
                                   (__attribute__((address_space(3))) void*)l, 16, 0, 0);
}

// ---------------- diagnostics: ws too small sentinel ----------------
__global__ void sentinel_kernel(float* out){ out[threadIdx.x] = 123456.0f; }

// ---------------- f32 -> bf16 convert (with zero tail padding) ----------------
__global__ void cvt_kernel(const float* __restrict__ in, u16* __restrict__ out,
                           long nin, long nout){
  long i = (long)blockIdx.x*blockDim.x + threadIdx.x;
  long stride = (long)gridDim.x*blockDim.x;
  for (; i < nout; i += stride) out[i] = (i < nin) ? f2bf(in[i]) : (u16)0;
}

// ---------------- bf16 MFMA GEMM, C[M,N] = A[M,K] * B[N,K]^T ----------------
// grid (M/128, N/128), 256 threads (4 waves, 2x2, each 64x64 out), BK=64.
template<int BF16OUT>
__global__ __launch_bounds__(256) void gemm_bt(const u16* __restrict__ A, const u16* __restrict__ B,
                                               void* __restrict__ Cv, int K, int ldc)
{
  __shared__ u16 As[128*64];
  __shared__ u16 Bs[128*64];
  const int tid = threadIdx.x, lane = tid & 63;
  const int wave = tid >> 6;
  const int wr = wave >> 1, wc = wave & 1;
  f32x4 acc[4][4];
  #pragma unroll
  for (int i=0;i<4;i++)
    #pragma unroll
    for (int j=0;j<4;j++) acc[i][j] = (f32x4){0.f,0.f,0.f,0.f};

  const u16* Ag = A + (size_t)blockIdx.x * 128 * K;
  const u16* Bg = B + (size_t)blockIdx.y * 128 * K;
  const u16* srcG = ((wave < 2) ? Ag : Bg) + (size_t)((wave & 1) * 64) * K;
  u16* dstL = ((wave < 2) ? As : Bs) + (wave & 1) * 64 * 64;
  const int lrow8 = lane >> 3;
  const int scol  = (lane & 7) ^ (lane >> 3);
  const int r = lane & 15, g = lane >> 4;

  for (int kt = 0; kt < K; kt += 64) {
    __syncthreads();
    #pragma unroll
    for (int i=0;i<8;i++){
      const u16* gp = srcG + (size_t)(i*8 + lrow8)*K + kt + scol*8;
      gload16(gp, dstL + i*512);
    }
    __syncthreads();
    #pragma unroll
    for (int kk=0;kk<2;kk++){
      bf16x8 af[4], bfv[4];
      #pragma unroll
      for (int mt=0;mt<4;mt++)
        af[mt] = *(const bf16x8*)&As[(wr*64+mt*16+r)*64 + (((kk*4+g) ^ (r&7))*8)];
      #pragma unroll
      for (int nt=0;nt<4;nt++)
        bfv[nt] = *(const bf16x8*)&Bs[(wc*64+nt*16+r)*64 + (((kk*4+g) ^ (r&7))*8)];
      #pragma unroll
      for (int mt=0;mt<4;mt++)
        #pragma unroll
        for (int nt=0;nt<4;nt++)
          acc[mt][nt] = mfma16(af[mt], bfv[nt], acc[mt][nt]);
    }
  }
  const size_t cbase = (size_t)(blockIdx.x*128 + wr*64 + g*4) * ldc
                     + blockIdx.y*128 + wc*64 + r;
  if (BF16OUT) {
    u16* Cg = (u16*)Cv + cbase;
    #pragma unroll
    for (int mt=0;mt<4;mt++)
      #pragma unroll
      for (int nt=0;nt<4;nt++)
        #pragma unroll
        for (int j=0;j<4;j++)
          Cg[(size_t)(mt*16+j)*ldc + nt*16] = f2bf(acc[mt][nt][j]);
  } else {
    float* Cg = (float*)Cv + cbase;
    #pragma unroll
    for (int mt=0;mt<4;mt++)
      #pragma unroll
      for (int nt=0;nt<4;nt++)
        #pragma unroll
        for (int j=0;j<4;j++)
          Cg[(size_t)(mt*16+j)*ldc + nt*16] = acc[mt][nt][j];
  }
}

// ---------------- depthwise conv + SiLU + dt softplus (4-row blocked, 320 thr) ----------------
__global__ __launch_bounds__(320) void conv_kernel(
    const u16* __restrict__ zxh, const float* __restrict__ cw, const float* __restrict__ cb,
    const float* __restrict__ dtb,
    u16* __restrict__ xout, u16* __restrict__ Bout, u16* __restrict__ Cout,
    float* __restrict__ dtt, int rev)
{
  const int L0 = blockIdx.x*4, b = blockIdx.y, tid = threadIdx.x;
  if (tid < 288){
    const int ch0 = tid*8;
    f32x4 cw4[8];
    #pragma unroll
    for (int j=0;j<8;j++) cw4[j] = *(const f32x4*)&cw[(ch0+j)*4];
    float bias[8];
    {
      f32x4 b0 = *(const f32x4*)&cb[ch0];
      f32x4 b1 = *(const f32x4*)&cb[ch0+4];
      #pragma unroll
      for (int j=0;j<4;j++){ bias[j] = b0[j]; bias[4+j] = b1[j]; }
    }
    u16x8 row[7];
    #pragma unroll
    for (int ri=0; ri<7; ++ri){
      const int ls = L0 - 3 + ri;
      if (ls >= 0){
        const int lsrc = rev ? (LSEQ-1-ls) : ls;
        row[ri] = *(const u16x8*)(zxh + ((size_t)b*LSEQ + lsrc)*NPAD + DINNER + ch0);
      } else {
        #pragma unroll
        for (int j=0;j<8;j++) row[ri][j] = 0;
      }
    }
    #pragma unroll
    for (int i=0;i<4;i++){
      float acc[8];
      #pragma unroll
      for (int j=0;j<8;j++) acc[j] = bias[j];
      #pragma unroll
      for (int k=0;k<4;k++){
        #pragma unroll
        for (int j=0;j<8;j++) acc[j] += cw4[j][k] * bf2f(row[i+k][j]);
      }
      u16x8 o;
      #pragma unroll
      for (int j=0;j<8;j++){
        float sv = acc[j] / (1.f + __expf(-acc[j]));
        o[j] = f2bf(sv);
      }
      const int l = L0 + i;
      if (ch0 < DINNER)
        *(u16x8*)(xout + ((size_t)b*LSEQ + l)*DINNER + ch0) = o;
      else if (ch0 < DINNER+DSTATE)
        *(u16x8*)(Bout + ((size_t)b*LSEQ + l)*DSTATE + (ch0 - DINNER)) = o;
      else
        *(u16x8*)(Cout + ((size_t)b*LSEQ + l)*DSTATE + (ch0 - DINNER - DSTATE)) = o;
    }
  } else {
    const int hh = tid - 288;
    const float dbv = dtb[hh];
    #pragma unroll
    for (int i=0;i<4;i++){
      const int l = L0 + i;
      const int lsrc = rev ? (LSEQ-1-l) : l;
      float raw = bf2f(zxh[((size_t)b*LSEQ + lsrc)*NPAD + DINNER + CONVDIM + hh]) + dbv;
      float dv = (raw > 20.f) ? raw : log1pf(__expf(raw));
      dtt[((size_t)b*NHEADS + hh)*LSEQ + l] = dv;
    }
  }
}

// ---------------- per-chunk inclusive cumsum of dt*A ----------------
__global__ __launch_bounds__(256) void acs_kernel(const float* __restrict__ dtt,
    const float* __restrict__ A_log, float* __restrict__ acs)
{
  const int c = blockIdx.x, hh = blockIdx.y, b = blockIdx.z;
  const int t = threadIdx.x;
  __shared__ float s[CHUNK];
  const float Ah = -__expf(A_log[hh]);
  const size_t base = ((size_t)b*NHEADS + hh)*LSEQ + (size_t)c*CHUNK;
  s[t] = dtt[base + t] * Ah;
  __syncthreads();
  for (int off=1; off<CHUNK; off<<=1){
    float add = (t >= off) ? s[t-off] : 0.f;
    __syncthreads();
    s[t] += add;
    __syncthreads();
  }
  acs[base + t] = s[t];
}

// ---------------- states kernel ----------------
__global__ __launch_bounds__(256) void states_kernel(
    const u16* __restrict__ xb, const u16* __restrict__ Bb,
    const float* __restrict__ dtt, const float* __restrict__ acs,
    u16* __restrict__ states)
{
  const int h = blockIdx.x, c = blockIdx.y, b = blockIdx.z;
  const int tid = threadIdx.x, lane = tid & 63, w = tid >> 6;
  __shared__ float acs_s[CHUNK], dt_s[CHUNK];
  __shared__ u32 xdtTW[64*20];
  __shared__ u32 BsdW[128*20];

  const size_t bhBase = ((size_t)b*NHEADS + h)*LSEQ + (size_t)c*CHUNK;
  acs_s[tid] = acs[bhBase + tid];
  dt_s[tid]  = dtt[bhBase + tid];
  __syncthreads();
  const float acsLast = acs_s[CHUNK-1];

  f32x4 sacc[4][2];
  #pragma unroll
  for (int i=0;i<4;i++){ sacc[i][0] = (f32x4){0,0,0,0}; sacc[i][1] = (f32x4){0,0,0,0}; }

  const int s2 = tid >> 4, q = tid & 15;
  const int g = lane >> 4, r = lane & 15;
  const size_t rowBase = (size_t)b*LSEQ + (size_t)c*CHUNK;
  for (int st8 = 0; st8 < 8; ++st8) {
    const int s0 = st8*32;
    const int sA = s0 + 2*s2, sB = sA + 1;
    u16x4 xA = *(const u16x4*)(xb + (rowBase+sA)*DINNER + h*HEADDIM + 4*q);
    u16x4 xB4 = *(const u16x4*)(xb + (rowBase+sB)*DINNER + h*HEADDIM + 4*q);
    u16x8 bA = *(const u16x8*)(Bb + (rowBase+sA)*DSTATE + 8*q);
    u16x8 bB = *(const u16x8*)(Bb + (rowBase+sB)*DSTATE + 8*q);
    const float dA = dt_s[sA], dB = dt_s[sB];
    const float eA = __expf(acsLast - acs_s[sA]), eB = __expf(acsLast - acs_s[sB]);
    __syncthreads();
    #pragma unroll
    for (int j=0;j<4;j++){
      int p = 4*q + j;
      xdtTW[p*20 + (s2 ^ (((p>>3)&3)<<2))] = pack2(bf2f(xA[j])*dA, bf2f(xB4[j])*dB);
    }
    #pragma unroll
    for (int j=0;j<8;j++){
      int n = 8*q + j;
      BsdW[n*20 + (s2 ^ (((n>>3)&3)<<2))] = pack2(bf2f(bA[j])*eA, bf2f(bB[j])*eB);
    }
    __syncthreads();
    bf16x8 xf[4];
    #pragma unroll
    for (int pt=0;pt<4;pt++){
      int p = pt*16 + r;
      xf[pt] = *(const bf16x8*)&xdtTW[p*20 + 4*(g ^ ((p>>3)&3))];
    }
    #pragma unroll
    for (int nt=0;nt<2;nt++){
      int n = w*32 + nt*16 + r;
      bf16x8 bdf = *(const bf16x8*)&BsdW[n*20 + 4*(g ^ ((n>>3)&3))];
      #pragma unroll
      for (int pt=0;pt<4;pt++) sacc[pt][nt] = mfma16(xf[pt], bdf, sacc[pt][nt]);
    }
  }
  u16* sp = states + (((size_t)b*NCHUNK + c)*NHEADS + h)*(size_t)(HEADDIM*DSTATE);
  #pragma unroll
  for (int pt=0;pt<4;pt++)
    #pragma unroll
    for (int nt=0;nt<2;nt++)
      #pragma unroll
      for (int j=0;j<4;j++)
        sp[(size_t)(pt*16+g*4+j)*DSTATE + w*32+nt*16+r] = f2bf(sacc[pt][nt][j]);
}

// ---------------- inter-chunk state recurrence (512 blocks) ----------------
__global__ __launch_bounds__(256) void recur_kernel(const u16* __restrict__ states,
    const float* __restrict__ acs, u16* __restrict__ prev)
{
  const int bx = blockIdx.x;
  const int seg = bx & 7, bh = bx >> 3;
  const int b = bh >> 5, h = bh & 31;
  const int tid = threadIdx.x;
  float S[4];
  #pragma unroll
  for (int k=0;k<4;k++) S[k] = 0.f;
  for (int c=0;c<NCHUNK;c++){
    const size_t off = (((size_t)b*NCHUNK + c)*NHEADS + h)*(size_t)(HEADDIM*DSTATE)
                     + seg*1024;
    const float dc = __expf(acs[((size_t)b*NHEADS+h)*LSEQ + (size_t)c*CHUNK + CHUNK-1]);
    #pragma unroll
    for (int k=0;k<4;k++){
      const size_t i = off + tid + k*256;
      prev[i] = f2bf(S[k]);
      S[k] = S[k]*dc + bf2f(states[i]);
    }
  }
}

// ---------------- merged Y kernel, HALF-SPLIT: each block does 8 strips (128 rows) ----------
// grid (NHEADS, NCHUNK*2, BSZ); half = by&1 selects strips [8*half, 8*half+8).
// Wave w owns local strips mt'*4+w (global GS = half*8 + mt'*4 + w, rows GS*16+[0,16)).
// half 0 runs only st8 = 0..3 (strips 0-7 inactive beyond). caf[2][4]+yacc[2][4]
// halves VGPR vs R10 form -> higher occupancy. Same barrier pattern per st8 step.
__global__ __launch_bounds__(256) void ydiagoff_kernel(
    const u16* __restrict__ xb, const u16* __restrict__ Bb, const u16* __restrict__ Cb,
    const float* __restrict__ dtt, const float* __restrict__ acs,
    const u16* __restrict__ prev, const float* __restrict__ Dp,
    u16* __restrict__ ydir)
{
  const int h = blockIdx.x;
  const int c = blockIdx.y >> 1, half = blockIdx.y & 1;
  const int b = blockIdx.z;
  const int tid = threadIdx.x, lane = tid & 63, w = tid >> 6;
  __shared__ float acs_s[CHUNK], dt_s[CHUNK];
  __shared__ u16 Bs[32][136];
  __shared__ u32 xdtTW[64*20];
  __shared__ u16 Ms[4][32][40];

  const size_t bhBase = ((size_t)b*NHEADS + h)*LSEQ + (size_t)c*CHUNK;
  acs_s[tid] = acs[bhBase + tid];
  dt_s[tid]  = dtt[bhBase + tid];
  __syncthreads();

  const int g = lane >> 4, r = lane & 15;
  const size_t rowBase = (size_t)b*LSEQ + (size_t)c*CHUNK;
  const u16* Crow = Cb + rowBase*DSTATE;

  bf16x8 caf[2][4];
  #pragma unroll
  for (int mt=0;mt<2;mt++){
    const int GS = half*8 + 4*mt + w;
    #pragma unroll
    for (int ks=0;ks<4;ks++)
      caf[mt][ks] = *(const bf16x8*)(Crow + (size_t)(GS*16+r)*DSTATE + ks*32 + g*8);
  }

  f32x4 yacc[2][4];
  #pragma unroll
  for (int i=0;i<2;i++)
    #pragma unroll
    for (int j=0;j<4;j++) yacc[i][j] = (f32x4){0,0,0,0};

  const int sl = tid >> 3, part = tid & 7;
  const int s2 = tid >> 4, q = tid & 15;
  const int nst = half ? 8 : 4;
  for (int st8 = 0; st8 < nst; ++st8) {
    const int s0 = st8*32;
    u16x8 v0 = *(const u16x8*)(Bb + (rowBase + s0 + sl)*DSTATE + part*16);
    u16x8 v1 = *(const u16x8*)(Bb + (rowBase + s0 + sl)*DSTATE + part*16 + 8);
    const int sA = s0 + 2*s2, sB = sA + 1;
    u16x4 xA = *(const u16x4*)(xb + (rowBase+sA)*DINNER + h*HEADDIM + 4*q);
    u16x4 xB4 = *(const u16x4*)(xb + (rowBase+sB)*DINNER + h*HEADDIM + 4*q);
    const float dA = dt_s[sA], dB = dt_s[sB];
    __syncthreads();
    *(u16x8*)&Bs[sl][part*16]   = v0;
    *(u16x8*)&Bs[sl][part*16+8] = v1;
    #pragma unroll
    for (int j=0;j<4;j++){
      int p = 4*q + j;
      xdtTW[p*20 + (s2 ^ (((p>>3)&3)<<2))] = pack2(bf2f(xA[j])*dA, bf2f(xB4[j])*dB);
    }
    __syncthreads();
    bf16x8 xf[4];
    #pragma unroll
    for (int pt=0;pt<4;pt++){
      int p = pt*16 + r;
      xf[pt] = *(const bf16x8*)&xdtTW[p*20 + 4*(g ^ ((p>>3)&3))];
    }
    #pragma unroll
    for (int mt=0;mt<2;mt++){
      const int GS = half*8 + 4*mt + w;
      if (GS >= 2*st8) {
        f32x4 g20 = (f32x4){0,0,0,0}, g21 = (f32x4){0,0,0,0};
        #pragma unroll
        for (int ks=0;ks<4;ks++){
          bf16x8 bfv0 = *(const bf16x8*)&Bs[r][ks*32+g*8];
          bf16x8 bfv1 = *(const bf16x8*)&Bs[16+r][ks*32+g*8];
          g20 = mfma16(caf[mt][ks], bfv0, g20);
          g21 = mfma16(caf[mt][ks], bfv1, g21);
        }
        #pragma unroll
        for (int j=0;j<4;j++){
          int tl = GS*16 + g*4 + j;
          int sg0 = s0 + r;
          int sg1 = s0 + 16 + r;
          float m0 = (sg0 <= tl) ? g20[j]*__expf(acs_s[tl]-acs_s[sg0]) : 0.f;
          float m1 = (sg1 <= tl) ? g21[j]*__expf(acs_s[tl]-acs_s[sg1]) : 0.f;
          Ms[w][mt*16+g*4+j][r]    = f2bf(m0);
          Ms[w][mt*16+g*4+j][16+r] = f2bf(m1);
        }
        bf16x8 mf = *(const bf16x8*)&Ms[w][mt*16+r][g*8];
        #pragma unroll
        for (int pt=0;pt<4;pt++) yacc[mt][pt] = mfma16(mf, xf[pt], yacc[mt][pt]);
      }
    }
  }
  // Y_off: scale caf rows by exp(acs_t), accumulate C*prev^T
  #pragma unroll
  for (int mt=0;mt<2;mt++){
    const int GS = half*8 + 4*mt + w;
    const float et = __expf(acs_s[GS*16 + r]);
    #pragma unroll
    for (int ks=0;ks<4;ks++)
      #pragma unroll
      for (int e=0;e<8;e++)
        caf[mt][ks][e] = (__bf16)((float)caf[mt][ks][e] * et);
  }
  const u16* pv = prev + (((size_t)b*NCHUNK + c)*NHEADS + h)*(size_t)(HEADDIM*DSTATE);
  #pragma unroll
  for (int ks=0;ks<4;ks++){
    bf16x8 pf[4];
    #pragma unroll
    for (int pt=0;pt<4;pt++)
      pf[pt] = *(const bf16x8*)(pv + (size_t)(pt*16+r)*DSTATE + ks*32 + g*8);
    #pragma unroll
    for (int mt=0;mt<2;mt++)
      #pragma unroll
      for (int pt=0;pt<4;pt++) yacc[mt][pt] = mfma16(caf[mt][ks], pf[pt], yacc[mt][pt]);
  }
  const float Dh = Dp[h];
  const u16* xrow = xb + rowBase*DINNER + h*HEADDIM;
  u16* yrow = ydir + rowBase*DINNER + h*HEADDIM;
  #pragma unroll
  for (int mt=0;mt<2;mt++){
    const int GS = half*8 + 4*mt + w;
    #pragma unroll
    for (int pt=0;pt<4;pt++)
      #pragma unroll
      for (int j=0;j<4;j++){
        int tl = GS*16 + g*4 + j;
        int p  = pt*16 + r;
        float xv = bf2f(xrow[(size_t)tl*DINNER + p]);
        yrow[(size_t)tl*DINNER + p] = f2bf(yacc[mt][pt][j] + xv*Dh);
      }
  }
}

// ---------------- gate (silu(z)) + RMSNorm + combine ----------------
__global__ __launch_bounds__(256) void gate_norm_kernel(
    const u16* __restrict__ ydir, const u16* __restrict__ zxh,
    const float* __restrict__ nw, u16* __restrict__ ybufh, int rev)
{
  const int l = blockIdx.x, b = blockIdx.y, tid = threadIdx.x;
  const int lsrc = rev ? (LSEQ-1-l) : l;
  u16x8 zv = *(const u16x8*)(zxh + ((size_t)b*LSEQ + lsrc)*NPAD + tid*8);
  u16x8 yv = *(const u16x8*)(ydir + ((size_t)b*LSEQ + l)*DINNER + tid*8);
  float gg[8]; float ss = 0.f;
  #pragma unroll
  for (int j=0;j<8;j++){
    float z = bf2f(zv[j]);
    float y = bf2f(yv[j]);
    float v = y * (z / (1.f + __expf(-z)));
    gg[j] = v; ss += v*v;
  }
  #pragma unroll
  for (int off=32; off>0; off>>=1) ss += __shfl_xor(ss, off, 64);
  __shared__ float red[4];
  if ((tid&63)==0) red[tid>>6] = ss;
  __syncthreads();
  float tot = red[0]+red[1]+red[2]+red[3];
  float scale = rsqrtf(tot * (1.f/DINNER) + 1e-5f);
  const float* nwp = nw + tid*8;
  u16* hrow = ybufh + ((size_t)b*LSEQ + lsrc)*DINNER + tid*8;
  u16x8 o;
  if (!rev){
    #pragma unroll
    for (int j=0;j<8;j++) o[j] = f2bf(0.5f * gg[j]*scale*nwp[j]);
  } else {
    u16x8 pvv = *(const u16x8*)hrow;
    #pragma unroll
    for (int j=0;j<8;j++) o[j] = f2bf(bf2f(pvv[j]) + 0.5f*gg[j]*scale*nwp[j]);
  }
  *(u16x8*)hrow = o;
}

extern "C" void kernel_launch(void* const* d_in, const int* in_sizes, int n_in,
                              void* d_out, int out_size, void* d_ws, size_t ws_size,
                              hipStream_t stream) {
  const float* u        = (const float*)d_in[0];
  const float* w1       = (const float*)d_in[1];
  const float* conv_w   = (const float*)d_in[2];
  const float* conv_b   = (const float*)d_in[3];
  const float* dt_bias  = (const float*)d_in[4];
  const float* A_log    = (const float*)d_in[5];
  const float* Dp       = (const float*)d_in[6];
  const float* norm_w   = (const float*)d_in[7];
  const float* bconv_w  = (const float*)d_in[8];
  const float* bconv_b  = (const float*)d_in[9];
  const float* bdt_bias = (const float*)d_in[10];
  const float* bA_log   = (const float*)d_in[11];
  const float* bDp      = (const float*)d_in[12];
  const float* bnorm_w  = (const float*)d_in[13];
  const float* wo       = (const float*)d_in[14];
  float* out = (float*)d_out;

  const size_t SZ_ZX  = (size_t)BL*NPAD*2;
  const size_t SZ_UB  = (size_t)BL*DMODEL*2;
  const size_t SZ_W1  = (size_t)NPAD*DMODEL*2;
  const size_t SZ_WO  = (size_t)DMODEL*DINNER*2;
  const size_t SZ_XB  = (size_t)BL*DINNER*2;
  const size_t SZ_BB  = (size_t)BL*DSTATE*2;
  const size_t SZ_DT  = (size_t)BSZ*NHEADS*LSEQ*4;
  const size_t SZ_ST  = (size_t)BSZ*NCHUNK*NHEADS*HEADDIM*DSTATE*2;
  const size_t SZ_YD  = (size_t)BL*DINNER*2;
  const size_t SZ_YH  = (size_t)BL*DINNER*2;
  const size_t NEED = SZ_ZX + SZ_UB + SZ_W1 + SZ_WO + SZ_XB + 2*SZ_BB + 2*SZ_DT
                    + SZ_ST + SZ_YD + SZ_YH;
  if (ws_size < NEED) { sentinel_kernel<<<1,256,0,stream>>>(out); return; }

  char* p = (char*)d_ws;
  u16*   zxh    = (u16*)p;              p += SZ_ZX;
  u16*   ub     = (u16*)p;              p += SZ_UB;
  u16*   states = ub;                   // alias: ub dead after in_proj GEMM
  u16*   w1b    = (u16*)p;              p += SZ_W1;
  u16*   wob    = (u16*)p;              p += SZ_WO;
  u16*   xb     = (u16*)p;              p += SZ_XB;
  u16*   Bb     = (u16*)p;              p += SZ_BB;
  u16*   Cb     = (u16*)p;              p += SZ_BB;
  float* dtt    = (float*)p;            p += SZ_DT;
  float* acs    = (float*)p;            p += SZ_DT;
  u16*   prev   = (u16*)p;              p += SZ_ST;
  u16*   ydir   = (u16*)p;              p += SZ_YD;
  u16*   ybufh  = (u16*)p;              p += SZ_YH;

  cvt_kernel<<<2048,256,0,stream>>>(u,  ub,  (long)BL*DMODEL,      (long)BL*DMODEL);
  cvt_kernel<<<2048,256,0,stream>>>(w1, w1b, (long)DINPROJ*DMODEL, (long)NPAD*DMODEL);
  cvt_kernel<<<2048,256,0,stream>>>(wo, wob, (long)DMODEL*DINNER,  (long)DMODEL*DINNER);

  gemm_bt<1><<<dim3(BL/128, NPAD/128),256,0,stream>>>(ub, w1b, zxh, DMODEL, NPAD);

  for (int dir = 0; dir < 2; ++dir) {
    const float* cwp = dir ? bconv_w  : conv_w;
    const float* cbp = dir ? bconv_b  : conv_b;
    const float* dbp = dir ? bdt_bias : dt_bias;
    const float* alp = dir ? bA_log   : A_log;
    const float* ddp = dir ? bDp      : Dp;
    const float* nwp = dir ? bnorm_w  : norm_w;
    conv_kernel<<<dim3(LSEQ/4,BSZ),320,0,stream>>>(zxh, cwp, cbp, dbp, xb, Bb, Cb, dtt, dir);
    acs_kernel<<<dim3(NCHUNK,NHEADS,BSZ),256,0,stream>>>(dtt, alp, acs);
    states_kernel<<<dim3(NHEADS,NCHUNK,BSZ),256,0,stream>>>(xb, Bb, dtt, acs, states);
    recur_kernel<<<BSZ*NHEADS*8,256,0,stream>>>(states, acs, prev);
    ydiagoff_kernel<<<dim3(NHEADS,NCHUNK*2,BSZ),256,0,stream>>>(xb, Bb, Cb, dtt, acs, prev, ddp, ydir);
    gate_norm_kernel<<<dim3(LSEQ,BSZ),256,0,stream>>>(ydir, zxh, nwp, ybufh, dir);
  }

  gemm_bt<0><<<dim3(BL/128, DMODEL/128),256,0,stream>>>(ybufh, wob, out, DINNER, DMODEL);
}

// Round 21
// 449.199 us; speedup vs baseline: 1.0577x; 1.0577x over previous
//
#include <hip/hip_runtime.h>

#define LSEQ 4096
#define BSZ 2
#define DMODEL 1024
#define DINNER 2048
#define NHEADS 32
#define HEADDIM 64
#define DSTATE 128
#define CHUNK 256
#define NCHUNK 16
#define CONVDIM 2304
#define DINPROJ 4384
#define NPAD 4480
#define BL (BSZ*LSEQ)

typedef unsigned short u16;
typedef unsigned int u32;
typedef u16 u16x4 __attribute__((ext_vector_type(4)));
typedef u16 u16x8 __attribute__((ext_vector_type(8)));
typedef __bf16 bf16x8 __attribute__((ext_vector_type(8)));
typedef float f32x4 __attribute__((ext_vector_type(4)));

__device__ __forceinline__ u16 f2bf(float f){
  union { float f; u32 u; } v; v.f = f;
  u32 r = v.u + 0x7fffu + ((v.u >> 16) & 1u);
  return (u16)(r >> 16);
}
__device__ __forceinline__ float bf2f(u16 h){
  union { u32 u; float f; } v; v.u = ((u32)h) << 16;
  return v.f;
}
__device__ __forceinline__ u32 pack2(float a, float b){
  return (u32)f2bf(a) | ((u32)f2bf(b) << 16);
}
__device__ __forceinline__ f32x4 mfma16(bf16x8 a, bf16x8 b, f32x4 c){
  return __builtin_amdgcn_mfma_f32_16x16x32_bf16(a, b, c, 0, 0, 0);
}
// async global->LDS, 16B per lane; LDS dest is wave-uniform base + lane*16
__device__ __forceinline__ void gload16(const void* g, void* l){
  __builtin_amdgcn_global_load_lds((const __attribute__((address_space(1))) void*)g,
                                   (__attribute__((address_space(3))) void*)l, 16, 0, 0);
}

// ---------------- diagnostics: ws too small sentinel ----------------
__global__ void sentinel_kernel(float* out){ out[threadIdx.x] = 123456.0f; }

// ---------------- f32 -> bf16 convert (with zero tail padding) ----------------
__global__ void cvt_kernel(const float* __restrict__ in, u16* __restrict__ out,
                           long nin, long nout){
  long i = (long)blockIdx.x*blockDim.x + threadIdx.x;
  long stride = (long)gridDim.x*blockDim.x;
  for (; i < nout; i += stride) out[i] = (i < nin) ? f2bf(in[i]) : (u16)0;
}

// ---------------- bf16 MFMA GEMM, C[M,N] = A[M,K] * B[N,K]^T ----------------
// grid (M/128, N/128), 256 threads (4 waves, 2x2, each 64x64 out), BK=64.
template<int BF16OUT>
__global__ __launch_bounds__(256) void gemm_bt(const u16* __restrict__ A, const u16* __restrict__ B,
                                               void* __restrict__ Cv, int K, int ldc)
{
  __shared__ u16 As[128*64];
  __shared__ u16 Bs[128*64];
  const int tid = threadIdx.x, lane = tid & 63;
  const int wave = tid >> 6;
  const int wr = wave >> 1, wc = wave & 1;
  f32x4 acc[4][4];
  #pragma unroll
  for (int i=0;i<4;i++)
    #pragma unroll
    for (int j=0;j<4;j++) acc[i][j] = (f32x4){0.f,0.f,0.f,0.f};

  const u16* Ag = A + (size_t)blockIdx.x * 128 * K;
  const u16* Bg = B + (size_t)blockIdx.y * 128 * K;
  const u16* srcG = ((wave < 2) ? Ag : Bg) + (size_t)((wave & 1) * 64) * K;
  u16* dstL = ((wave < 2) ? As : Bs) + (wave & 1) * 64 * 64;
  const int lrow8 = lane >> 3;
  const int scol  = (lane & 7) ^ (lane >> 3);
  const int r = lane & 15, g = lane >> 4;

  for (int kt = 0; kt < K; kt += 64) {
    __syncthreads();
    #pragma unroll
    for (int i=0;i<8;i++){
      const u16* gp = srcG + (size_t)(i*8 + lrow8)*K + kt + scol*8;
      gload16(gp, dstL + i*512);
    }
    __syncthreads();
    #pragma unroll
    for (int kk=0;kk<2;kk++){
      bf16x8 af[4], bfv[4];
      #pragma unroll
      for (int mt=0;mt<4;mt++)
        af[mt] = *(const bf16x8*)&As[(wr*64+mt*16+r)*64 + (((kk*4+g) ^ (r&7))*8)];
      #pragma unroll
      for (int nt=0;nt<4;nt++)
        bfv[nt] = *(const bf16x8*)&Bs[(wc*64+nt*16+r)*64 + (((kk*4+g) ^ (r&7))*8)];
      #pragma unroll
      for (int mt=0;mt<4;mt++)
        #pragma unroll
        for (int nt=0;nt<4;nt++)
          acc[mt][nt] = mfma16(af[mt], bfv[nt], acc[mt][nt]);
    }
  }
  const size_t cbase = (size_t)(blockIdx.x*128 + wr*64 + g*4) * ldc
                     + blockIdx.y*128 + wc*64 + r;
  if (BF16OUT) {
    u16* Cg = (u16*)Cv + cbase;
    #pragma unroll
    for (int mt=0;mt<4;mt++)
      #pragma unroll
      for (int nt=0;nt<4;nt++)
        #pragma unroll
        for (int j=0;j<4;j++)
          Cg[(size_t)(mt*16+j)*ldc + nt*16] = f2bf(acc[mt][nt][j]);
  } else {
    float* Cg = (float*)Cv + cbase;
    #pragma unroll
    for (int mt=0;mt<4;mt++)
      #pragma unroll
      for (int nt=0;nt<4;nt++)
        #pragma unroll
        for (int j=0;j<4;j++)
          Cg[(size_t)(mt*16+j)*ldc + nt*16] = acc[mt][nt][j];
  }
}

// ---------------- depthwise conv + SiLU + dt softplus (4-row blocked, 320 thr) ----------------
__global__ __launch_bounds__(320) void conv_kernel(
    const u16* __restrict__ zxh, const float* __restrict__ cw, const float* __restrict__ cb,
    const float* __restrict__ dtb,
    u16* __restrict__ xout, u16* __restrict__ Bout, u16* __restrict__ Cout,
    float* __restrict__ dtt, int rev)
{
  const int L0 = blockIdx.x*4, b = blockIdx.y, tid = threadIdx.x;
  if (tid < 288){
    const int ch0 = tid*8;
    f32x4 cw4[8];
    #pragma unroll
    for (int j=0;j<8;j++) cw4[j] = *(const f32x4*)&cw[(ch0+j)*4];
    float bias[8];
    {
      f32x4 b0 = *(const f32x4*)&cb[ch0];
      f32x4 b1 = *(const f32x4*)&cb[ch0+4];
      #pragma unroll
      for (int j=0;j<4;j++){ bias[j] = b0[j]; bias[4+j] = b1[j]; }
    }
    u16x8 row[7];
    #pragma unroll
    for (int ri=0; ri<7; ++ri){
      const int ls = L0 - 3 + ri;
      if (ls >= 0){
        const int lsrc = rev ? (LSEQ-1-ls) : ls;
        row[ri] = *(const u16x8*)(zxh + ((size_t)b*LSEQ + lsrc)*NPAD + DINNER + ch0);
      } else {
        #pragma unroll
        for (int j=0;j<8;j++) row[ri][j] = 0;
      }
    }
    #pragma unroll
    for (int i=0;i<4;i++){
      float acc[8];
      #pragma unroll
      for (int j=0;j<8;j++) acc[j] = bias[j];
      #pragma unroll
      for (int k=0;k<4;k++){
        #pragma unroll
        for (int j=0;j<8;j++) acc[j] += cw4[j][k] * bf2f(row[i+k][j]);
      }
      u16x8 o;
      #pragma unroll
      for (int j=0;j<8;j++){
        float sv = acc[j] / (1.f + __expf(-acc[j]));
        o[j] = f2bf(sv);
      }
      const int l = L0 + i;
      if (ch0 < DINNER)
        *(u16x8*)(xout + ((size_t)b*LSEQ + l)*DINNER + ch0) = o;
      else if (ch0 < DINNER+DSTATE)
        *(u16x8*)(Bout + ((size_t)b*LSEQ + l)*DSTATE + (ch0 - DINNER)) = o;
      else
        *(u16x8*)(Cout + ((size_t)b*LSEQ + l)*DSTATE + (ch0 - DINNER - DSTATE)) = o;
    }
  } else {
    const int hh = tid - 288;
    const float dbv = dtb[hh];
    #pragma unroll
    for (int i=0;i<4;i++){
      const int l = L0 + i;
      const int lsrc = rev ? (LSEQ-1-l) : l;
      float raw = bf2f(zxh[((size_t)b*LSEQ + lsrc)*NPAD + DINNER + CONVDIM + hh]) + dbv;
      float dv = (raw > 20.f) ? raw : log1pf(__expf(raw));
      dtt[((size_t)b*NHEADS + hh)*LSEQ + l] = dv;
    }
  }
}

// ---------------- per-chunk inclusive cumsum of dt*A ----------------
__global__ __launch_bounds__(256) void acs_kernel(const float* __restrict__ dtt,
    const float* __restrict__ A_log, float* __restrict__ acs)
{
  const int c = blockIdx.x, hh = blockIdx.y, b = blockIdx.z;
  const int t = threadIdx.x;
  __shared__ float s[CHUNK];
  const float Ah = -__expf(A_log[hh]);
  const size_t base = ((size_t)b*NHEADS + hh)*LSEQ + (size_t)c*CHUNK;
  s[t] = dtt[base + t] * Ah;
  __syncthreads();
  for (int off=1; off<CHUNK; off<<=1){
    float add = (t >= off) ? s[t-off] : 0.f;
    __syncthreads();
    s[t] += add;
    __syncthreads();
  }
  acs[base + t] = s[t];
}

// ---------------- states kernel ----------------
__global__ __launch_bounds__(256) void states_kernel(
    const u16* __restrict__ xb, const u16* __restrict__ Bb,
    const float* __restrict__ dtt, const float* __restrict__ acs,
    u16* __restrict__ states)
{
  const int h = blockIdx.x, c = blockIdx.y, b = blockIdx.z;
  const int tid = threadIdx.x, lane = tid & 63, w = tid >> 6;
  __shared__ float acs_s[CHUNK], dt_s[CHUNK];
  __shared__ u32 xdtTW[64*20];
  __shared__ u32 BsdW[128*20];

  const size_t bhBase = ((size_t)b*NHEADS + h)*LSEQ + (size_t)c*CHUNK;
  acs_s[tid] = acs[bhBase + tid];
  dt_s[tid]  = dtt[bhBase + tid];
  __syncthreads();
  const float acsLast = acs_s[CHUNK-1];

  f32x4 sacc[4][2];
  #pragma unroll
  for (int i=0;i<4;i++){ sacc[i][0] = (f32x4){0,0,0,0}; sacc[i][1] = (f32x4){0,0,0,0}; }

  const int s2 = tid >> 4, q = tid & 15;
  const int g = lane >> 4, r = lane & 15;
  const size_t rowBase = (size_t)b*LSEQ + (size_t)c*CHUNK;
  for (int st8 = 0; st8 < 8; ++st8) {
    const int s0 = st8*32;
    const int sA = s0 + 2*s2, sB = sA + 1;
    u16x4 xA = *(const u16x4*)(xb + (rowBase+sA)*DINNER + h*HEADDIM + 4*q);
    u16x4 xB4 = *(const u16x4*)(xb + (rowBase+sB)*DINNER + h*HEADDIM + 4*q);
    u16x8 bA = *(const u16x8*)(Bb + (rowBase+sA)*DSTATE + 8*q);
    u16x8 bB = *(const u16x8*)(Bb + (rowBase+sB)*DSTATE + 8*q);
    const float dA = dt_s[sA], dB = dt_s[sB];
    const float eA = __expf(acsLast - acs_s[sA]), eB = __expf(acsLast - acs_s[sB]);
    __syncthreads();
    #pragma unroll
    for (int j=0;j<4;j++){
      int p = 4*q + j;
      xdtTW[p*20 + (s2 ^ (((p>>3)&3)<<2))] = pack2(bf2f(xA[j])*dA, bf2f(xB4[j])*dB);
    }
    #pragma unroll
    for (int j=0;j<8;j++){
      int n = 8*q + j;
      BsdW[n*20 + (s2 ^ (((n>>3)&3)<<2))] = pack2(bf2f(bA[j])*eA, bf2f(bB[j])*eB);
    }
    __syncthreads();
    bf16x8 xf[4];
    #pragma unroll
    for (int pt=0;pt<4;pt++){
      int p = pt*16 + r;
      xf[pt] = *(const bf16x8*)&xdtTW[p*20 + 4*(g ^ ((p>>3)&3))];
    }
    #pragma unroll
    for (int nt=0;nt<2;nt++){
      int n = w*32 + nt*16 + r;
      bf16x8 bdf = *(const bf16x8*)&BsdW[n*20 + 4*(g ^ ((n>>3)&3))];
      #pragma unroll
      for (int pt=0;pt<4;pt++) sacc[pt][nt] = mfma16(xf[pt], bdf, sacc[pt][nt]);
    }
  }
  u16* sp = states + (((size_t)b*NCHUNK + c)*NHEADS + h)*(size_t)(HEADDIM*DSTATE);
  #pragma unroll
  for (int pt=0;pt<4;pt++)
    #pragma unroll
    for (int nt=0;nt<2;nt++)
      #pragma unroll
      for (int j=0;j<4;j++)
        sp[(size_t)(pt*16+g*4+j)*DSTATE + w*32+nt*16+r] = f2bf(sacc[pt][nt][j]);
}

// ---------------- inter-chunk state recurrence (512 blocks) ----------------
__global__ __launch_bounds__(256) void recur_kernel(const u16* __restrict__ states,
    const float* __restrict__ acs, u16* __restrict__ prev)
{
  const int bx = blockIdx.x;
  const int seg = bx & 7, bh = bx >> 3;
  const int b = bh >> 5, h = bh & 31;
  const int tid = threadIdx.x;
  float S[4];
  #pragma unroll
  for (int k=0;k<4;k++) S[k] = 0.f;
  for (int c=0;c<NCHUNK;c++){
    const size_t off = (((size_t)b*NCHUNK + c)*NHEADS + h)*(size_t)(HEADDIM*DSTATE)
                     + seg*1024;
    const float dc = __expf(acs[((size_t)b*NHEADS+h)*LSEQ + (size_t)c*CHUNK + CHUNK-1]);
    #pragma unroll
    for (int k=0;k<4;k++){
      const size_t i = off + tid + k*256;
      prev[i] = f2bf(S[k]);
      S[k] = S[k]*dc + bf2f(states[i]);
    }
  }
}

// ---------------- merged Y kernel: Y = Y_diag + exp(Acs)*C*prev^T + D*x ----------------
// Strip-interleaved wave mapping: wave w owns 16-row strips ms = mt*4 + w,
// i.e. t-rows mt*64 + w*16 + [0,16). Strip inactive for s-block st8 when
// 4*mt+w < 2*st8 -> skip G MFMA, exp masking, Ydiag MFMA. (R10/R17-proven form,
// 144 VGPR held-caf: beats ks-outer (R9), HBM-G (R11), transient-C (R12),
// half-split (R20) -- staging amortization over all 16 strips wins.)
__global__ __launch_bounds__(256) void ydiagoff_kernel(
    const u16* __restrict__ xb, const u16* __restrict__ Bb, const u16* __restrict__ Cb,
    const float* __restrict__ dtt, const float* __restrict__ acs,
    const u16* __restrict__ prev, const float* __restrict__ Dp,
    u16* __restrict__ ydir)
{
  const int h = blockIdx.x, c = blockIdx.y, b = blockIdx.z;
  const int tid = threadIdx.x, lane = tid & 63, w = tid >> 6;
  __shared__ float acs_s[CHUNK], dt_s[CHUNK];
  __shared__ u16 Bs[32][136];
  __shared__ u32 xdtTW[64*20];
  __shared__ u16 Ms[4][64][40];

  const size_t bhBase = ((size_t)b*NHEADS + h)*LSEQ + (size_t)c*CHUNK;
  acs_s[tid] = acs[bhBase + tid];
  dt_s[tid]  = dtt[bhBase + tid];
  __syncthreads();

  const int g = lane >> 4, r = lane & 15;
  const size_t rowBase = (size_t)b*LSEQ + (size_t)c*CHUNK;

  bf16x8 caf[4][4];
  const u16* Crow = Cb + rowBase*DSTATE;
  #pragma unroll
  for (int mt=0;mt<4;mt++)
    #pragma unroll
    for (int ks=0;ks<4;ks++)
      caf[mt][ks] = *(const bf16x8*)(Crow + (size_t)(mt*64+w*16+r)*DSTATE + ks*32 + g*8);

  f32x4 yacc[4][4];
  #pragma unroll
  for (int i=0;i<4;i++)
    #pragma unroll
    for (int j=0;j<4;j++) yacc[i][j] = (f32x4){0,0,0,0};

  const int sl = tid >> 3, part = tid & 7;
  const int s2 = tid >> 4, q = tid & 15;
  for (int st8 = 0; st8 < 8; ++st8) {
    const int s0 = st8*32;
    u16x8 v0 = *(const u16x8*)(Bb + (rowBase + s0 + sl)*DSTATE + part*16);
    u16x8 v1 = *(const u16x8*)(Bb + (rowBase + s0 + sl)*DSTATE + part*16 + 8);
    const int sA = s0 + 2*s2, sB = sA + 1;
    u16x4 xA = *(const u16x4*)(xb + (rowBase+sA)*DINNER + h*HEADDIM + 4*q);
    u16x4 xB4 = *(const u16x4*)(xb + (rowBase+sB)*DINNER + h*HEADDIM + 4*q);
    const float dA = dt_s[sA], dB = dt_s[sB];
    __syncthreads();
    *(u16x8*)&Bs[sl][part*16]   = v0;
    *(u16x8*)&Bs[sl][part*16+8] = v1;
    #pragma unroll
    for (int j=0;j<4;j++){
      int p = 4*q + j;
      xdtTW[p*20 + (s2 ^ (((p>>3)&3)<<2))] = pack2(bf2f(xA[j])*dA, bf2f(xB4[j])*dB);
    }
    __syncthreads();
    bf16x8 xf[4];
    #pragma unroll
    for (int pt=0;pt<4;pt++){
      int p = pt*16 + r;
      xf[pt] = *(const bf16x8*)&xdtTW[p*20 + 4*(g ^ ((p>>3)&3))];
    }
    #pragma unroll
    for (int mt=0;mt<4;mt++){
      if (4*mt + w >= 2*st8) {
        f32x4 g20 = (f32x4){0,0,0,0}, g21 = (f32x4){0,0,0,0};
        #pragma unroll
        for (int ks=0;ks<4;ks++){
          bf16x8 bfv0 = *(const bf16x8*)&Bs[r][ks*32+g*8];
          bf16x8 bfv1 = *(const bf16x8*)&Bs[16+r][ks*32+g*8];
          g20 = mfma16(caf[mt][ks], bfv0, g20);
          g21 = mfma16(caf[mt][ks], bfv1, g21);
        }
        #pragma unroll
        for (int j=0;j<4;j++){
          int tl = mt*64 + w*16 + g*4 + j;
          int sg0 = s0 + r;
          int sg1 = s0 + 16 + r;
          float m0 = (sg0 <= tl) ? g20[j]*__expf(acs_s[tl]-acs_s[sg0]) : 0.f;
          float m1 = (sg1 <= tl) ? g21[j]*__expf(acs_s[tl]-acs_s[sg1]) : 0.f;
          Ms[w][mt*16+g*4+j][r]    = f2bf(m0);
          Ms[w][mt*16+g*4+j][16+r] = f2bf(m1);
        }
        bf16x8 mf = *(const bf16x8*)&Ms[w][mt*16+r][g*8];
        #pragma unroll
        for (int pt=0;pt<4;pt++) yacc[mt][pt] = mfma16(mf, xf[pt], yacc[mt][pt]);
      }
    }
  }
  // Y_off: scale caf rows by exp(acs_t), accumulate C*prev^T
  #pragma unroll
  for (int mt=0;mt<4;mt++){
    const float et = __expf(acs_s[mt*64 + w*16 + r]);
    #pragma unroll
    for (int ks=0;ks<4;ks++)
      #pragma unroll
      for (int e=0;e<8;e++)
        caf[mt][ks][e] = (__bf16)((float)caf[mt][ks][e] * et);
  }
  const u16* pv = prev + (((size_t)b*NCHUNK + c)*NHEADS + h)*(size_t)(HEADDIM*DSTATE);
  #pragma unroll
  for (int ks=0;ks<4;ks++){
    bf16x8 pf[4];
    #pragma unroll
    for (int pt=0;pt<4;pt++)
      pf[pt] = *(const bf16x8*)(pv + (size_t)(pt*16+r)*DSTATE + ks*32 + g*8);
    #pragma unroll
    for (int mt=0;mt<4;mt++)
      #pragma unroll
      for (int pt=0;pt<4;pt++) yacc[mt][pt] = mfma16(caf[mt][ks], pf[pt], yacc[mt][pt]);
  }
  const float Dh = Dp[h];
  const u16* xrow = xb + rowBase*DINNER + h*HEADDIM;
  u16* yrow = ydir + rowBase*DINNER + h*HEADDIM;
  #pragma unroll
  for (int mt=0;mt<4;mt++)
    #pragma unroll
    for (int pt=0;pt<4;pt++)
      #pragma unroll
      for (int j=0;j<4;j++){
        int tl = mt*64 + w*16 + g*4 + j;
        int p  = pt*16 + r;
        float xv = bf2f(xrow[(size_t)tl*DINNER + p]);
        yrow[(size_t)tl*DINNER + p] = f2bf(yacc[mt][pt][j] + xv*Dh);
      }
}

// ---------------- gate (silu(z)) + RMSNorm + combine ----------------
__global__ __launch_bounds__(256) void gate_norm_kernel(
    const u16* __restrict__ ydir, const u16* __restrict__ zxh,
    const float* __restrict__ nw, u16* __restrict__ ybufh, int rev)
{
  const int l = blockIdx.x, b = blockIdx.y, tid = threadIdx.x;
  const int lsrc = rev ? (LSEQ-1-l) : l;
  u16x8 zv = *(const u16x8*)(zxh + ((size_t)b*LSEQ + lsrc)*NPAD + tid*8);
  u16x8 yv = *(const u16x8*)(ydir + ((size_t)b*LSEQ + l)*DINNER + tid*8);
  float gg[8]; float ss = 0.f;
  #pragma unroll
  for (int j=0;j<8;j++){
    float z = bf2f(zv[j]);
    float y = bf2f(yv[j]);
    float v = y * (z / (1.f + __expf(-z)));
    gg[j] = v; ss += v*v;
  }
  #pragma unroll
  for (int off=32; off>0; off>>=1) ss += __shfl_xor(ss, off, 64);
  __shared__ float red[4];
  if ((tid&63)==0) red[tid>>6] = ss;
  __syncthreads();
  float tot = red[0]+red[1]+red[2]+red[3];
  float scale = rsqrtf(tot * (1.f/DINNER) + 1e-5f);
  const float* nwp = nw + tid*8;
  u16* hrow = ybufh + ((size_t)b*LSEQ + lsrc)*DINNER + tid*8;
  u16x8 o;
  if (!rev){
    #pragma unroll
    for (int j=0;j<8;j++) o[j] = f2bf(0.5f * gg[j]*scale*nwp[j]);
  } else {
    u16x8 pvv = *(const u16x8*)hrow;
    #pragma unroll
    for (int j=0;j<8;j++) o[j] = f2bf(bf2f(pvv[j]) + 0.5f*gg[j]*scale*nwp[j]);
  }
  *(u16x8*)hrow = o;
}

extern "C" void kernel_launch(void* const* d_in, const int* in_sizes, int n_in,
                              void* d_out, int out_size, void* d_ws, size_t ws_size,
                              hipStream_t stream) {
  const float* u        = (const float*)d_in[0];
  const float* w1       = (const float*)d_in[1];
  const float* conv_w   = (const float*)d_in[2];
  const float* conv_b   = (const float*)d_in[3];
  const float* dt_bias  = (const float*)d_in[4];
  const float* A_log    = (const float*)d_in[5];
  const float* Dp       = (const float*)d_in[6];
  const float* norm_w   = (const float*)d_in[7];
  const float* bconv_w  = (const float*)d_in[8];
  const float* bconv_b  = (const float*)d_in[9];
  const float* bdt_bias = (const float*)d_in[10];
  const float* bA_log   = (const float*)d_in[11];
  const float* bDp      = (const float*)d_in[12];
  const float* bnorm_w  = (const float*)d_in[13];
  const float* wo       = (const float*)d_in[14];
  float* out = (float*)d_out;

  const size_t SZ_ZX  = (size_t)BL*NPAD*2;
  const size_t SZ_UB  = (size_t)BL*DMODEL*2;
  const size_t SZ_W1  = (size_t)NPAD*DMODEL*2;
  const size_t SZ_WO  = (size_t)DMODEL*DINNER*2;
  const size_t SZ_XB  = (size_t)BL*DINNER*2;
  const size_t SZ_BB  = (size_t)BL*DSTATE*2;
  const size_t SZ_DT  = (size_t)BSZ*NHEADS*LSEQ*4;
  const size_t SZ_ST  = (size_t)BSZ*NCHUNK*NHEADS*HEADDIM*DSTATE*2;
  const size_t SZ_YD  = (size_t)BL*DINNER*2;
  const size_t SZ_YH  = (size_t)BL*DINNER*2;
  const size_t NEED = SZ_ZX + SZ_UB + SZ_W1 + SZ_WO + SZ_XB + 2*SZ_BB + 2*SZ_DT
                    + SZ_ST + SZ_YD + SZ_YH;
  if (ws_size < NEED) { sentinel_kernel<<<1,256,0,stream>>>(out); return; }

  char* p = (char*)d_ws;
  u16*   zxh    = (u16*)p;              p += SZ_ZX;
  u16*   ub     = (u16*)p;              p += SZ_UB;
  u16*   states = ub;                   // alias: ub dead after in_proj GEMM
  u16*   w1b    = (u16*)p;              p += SZ_W1;
  u16*   wob    = (u16*)p;              p += SZ_WO;
  u16*   xb     = (u16*)p;              p += SZ_XB;
  u16*   Bb     = (u16*)p;              p += SZ_BB;
  u16*   Cb     = (u16*)p;              p += SZ_BB;
  float* dtt    = (float*)p;            p += SZ_DT;
  float* acs    = (float*)p;            p += SZ_DT;
  u16*   prev   = (u16*)p;              p += SZ_ST;
  u16*   ydir   = (u16*)p;              p += SZ_YD;
  u16*   ybufh  = (u16*)p;              p += SZ_YH;

  cvt_kernel<<<2048,256,0,stream>>>(u,  ub,  (long)BL*DMODEL,      (long)BL*DMODEL);
  cvt_kernel<<<2048,256,0,stream>>>(w1, w1b, (long)DINPROJ*DMODEL, (long)NPAD*DMODEL);
  cvt_kernel<<<2048,256,0,stream>>>(wo, wob, (long)DMODEL*DINNER,  (long)DMODEL*DINNER);

  gemm_bt<1><<<dim3(BL/128, NPAD/128),256,0,stream>>>(ub, w1b, zxh, DMODEL, NPAD);

  for (int dir = 0; dir < 2; ++dir) {
    const float* cwp = dir ? bconv_w  : conv_w;
    const float* cbp = dir ? bconv_b  : conv_b;
    const float* dbp = dir ? bdt_bias : dt_bias;
    const float* alp = dir ? bA_log   : A_log;
    const float* ddp = dir ? bDp      : Dp;
    const float* nwp = dir ? bnorm_w  : norm_w;
    conv_kernel<<<dim3(LSEQ/4,BSZ),320,0,stream>>>(zxh, cwp, cbp, dbp, xb, Bb, Cb, dtt, dir);
    acs_kernel<<<dim3(NCHUNK,NHEADS,BSZ),256,0,stream>>>(dtt, alp, acs);
    states_kernel<<<dim3(NHEADS,NCHUNK,BSZ),256,0,stream>>>(xb, Bb, dtt, acs, states);
    recur_kernel<<<BSZ*NHEADS*8,256,0,stream>>>(states, acs, prev);
    ydiagoff_kernel<<<dim3(NHEADS,NCHUNK,BSZ),256,0,stream>>>(xb, Bb, Cb, dtt, acs, prev, ddp, ydir);
    gate_norm_kernel<<<dim3(LSEQ,BSZ),256,0,stream>>>(ydir, zxh, nwp, ybufh, dir);
  }

  gemm_bt<0><<<dim3(BL/128, DMODEL/128),256,0,stream>>>(ybufh, wob, out, DINNER, DMODEL);
}

// Round 22
// 441.849 us; speedup vs baseline: 1.0753x; 1.0166x over previous
//
#include <hip/hip_runtime.h>

#define LSEQ 4096
#define BSZ 2
#define DMODEL 1024
#define DINNER 2048
#define NHEADS 32
#define HEADDIM 64
#define DSTATE 128
#define CHUNK 256
#define NCHUNK 16
#define CONVDIM 2304
#define DINPROJ 4384
#define NPAD 4480
#define BL (BSZ*LSEQ)

typedef unsigned short u16;
typedef unsigned int u32;
typedef u16 u16x4 __attribute__((ext_vector_type(4)));
typedef u16 u16x8 __attribute__((ext_vector_type(8)));
typedef __bf16 bf16x8 __attribute__((ext_vector_type(8)));
typedef float f32x4 __attribute__((ext_vector_type(4)));

__device__ __forceinline__ u16 f2bf(float f){
  union { float f; u32 u; } v; v.f = f;
  u32 r = v.u + 0x7fffu + ((v.u >> 16) & 1u);
  return (u16)(r >> 16);
}
__device__ __forceinline__ float bf2f(u16 h){
  union { u32 u; float f; } v; v.u = ((u32)h) << 16;
  return v.f;
}
__device__ __forceinline__ u32 pack2(float a, float b){
  return (u32)f2bf(a) | ((u32)f2bf(b) << 16);
}
__device__ __forceinline__ f32x4 mfma16(bf16x8 a, bf16x8 b, f32x4 c){
  return __builtin_amdgcn_mfma_f32_16x16x32_bf16(a, b, c, 0, 0, 0);
}
// async global->LDS, 16B per lane; LDS dest is wave-uniform base + lane*16
__device__ __forceinline__ void gload16(const void* g, void* l){
  __builtin_amdgcn_global_load_lds((const __attribute__((address_space(1))) void*)g,
                                   (__attribute__((address_space(3))) void*)l, 16, 0, 0);
}

// ---------------- diagnostics: ws too small sentinel ----------------
__global__ void sentinel_kernel(float* out){ out[threadIdx.x] = 123456.0f; }

// ---------------- fused f32 -> bf16 convert for u, W1 (padded), Wout ----------------
__global__ void cvt3_kernel(const float* __restrict__ a, u16* __restrict__ oa, long na,
                            const float* __restrict__ bb, u16* __restrict__ ob, long nb_in, long nb_out,
                            const float* __restrict__ cc, u16* __restrict__ oc, long nc)
{
  const long i0 = (long)blockIdx.x*blockDim.x + threadIdx.x;
  const long stride = (long)gridDim.x*blockDim.x;
  for (long i=i0; i<na; i+=stride) oa[i] = f2bf(a[i]);
  for (long i=i0; i<nb_out; i+=stride) ob[i] = (i < nb_in) ? f2bf(bb[i]) : (u16)0;
  for (long i=i0; i<nc; i+=stride) oc[i] = f2bf(cc[i]);
}

// ---------------- bf16 MFMA GEMM, C[M,N] = A[M,K] * B[N,K]^T ----------------
// grid (M/128, N/128), 256 threads (4 waves, 2x2, each 64x64 out), BK=64.
template<int BF16OUT>
__global__ __launch_bounds__(256) void gemm_bt(const u16* __restrict__ A, const u16* __restrict__ B,
                                               void* __restrict__ Cv, int K, int ldc)
{
  __shared__ u16 As[128*64];
  __shared__ u16 Bs[128*64];
  const int tid = threadIdx.x, lane = tid & 63;
  const int wave = tid >> 6;
  const int wr = wave >> 1, wc = wave & 1;
  f32x4 acc[4][4];
  #pragma unroll
  for (int i=0;i<4;i++)
    #pragma unroll
    for (int j=0;j<4;j++) acc[i][j] = (f32x4){0.f,0.f,0.f,0.f};

  const u16* Ag = A + (size_t)blockIdx.x * 128 * K;
  const u16* Bg = B + (size_t)blockIdx.y * 128 * K;
  const u16* srcG = ((wave < 2) ? Ag : Bg) + (size_t)((wave & 1) * 64) * K;
  u16* dstL = ((wave < 2) ? As : Bs) + (wave & 1) * 64 * 64;
  const int lrow8 = lane >> 3;
  const int scol  = (lane & 7) ^ (lane >> 3);
  const int r = lane & 15, g = lane >> 4;

  for (int kt = 0; kt < K; kt += 64) {
    __syncthreads();
    #pragma unroll
    for (int i=0;i<8;i++){
      const u16* gp = srcG + (size_t)(i*8 + lrow8)*K + kt + scol*8;
      gload16(gp, dstL + i*512);
    }
    __syncthreads();
    #pragma unroll
    for (int kk=0;kk<2;kk++){
      bf16x8 af[4], bfv[4];
      #pragma unroll
      for (int mt=0;mt<4;mt++)
        af[mt] = *(const bf16x8*)&As[(wr*64+mt*16+r)*64 + (((kk*4+g) ^ (r&7))*8)];
      #pragma unroll
      for (int nt=0;nt<4;nt++)
        bfv[nt] = *(const bf16x8*)&Bs[(wc*64+nt*16+r)*64 + (((kk*4+g) ^ (r&7))*8)];
      #pragma unroll
      for (int mt=0;mt<4;mt++)
        #pragma unroll
        for (int nt=0;nt<4;nt++)
          acc[mt][nt] = mfma16(af[mt], bfv[nt], acc[mt][nt]);
    }
  }
  const size_t cbase = (size_t)(blockIdx.x*128 + wr*64 + g*4) * ldc
                     + blockIdx.y*128 + wc*64 + r;
  if (BF16OUT) {
    u16* Cg = (u16*)Cv + cbase;
    #pragma unroll
    for (int mt=0;mt<4;mt++)
      #pragma unroll
      for (int nt=0;nt<4;nt++)
        #pragma unroll
        for (int j=0;j<4;j++)
          Cg[(size_t)(mt*16+j)*ldc + nt*16] = f2bf(acc[mt][nt][j]);
  } else {
    float* Cg = (float*)Cv + cbase;
    #pragma unroll
    for (int mt=0;mt<4;mt++)
      #pragma unroll
      for (int nt=0;nt<4;nt++)
        #pragma unroll
        for (int j=0;j<4;j++)
          Cg[(size_t)(mt*16+j)*ldc + nt*16] = acc[mt][nt][j];
  }
}

// ---------------- depthwise conv + SiLU + dt softplus (4-row blocked, 320 thr) ----------------
__global__ __launch_bounds__(320) void conv_kernel(
    const u16* __restrict__ zxh, const float* __restrict__ cw, const float* __restrict__ cb,
    const float* __restrict__ dtb,
    u16* __restrict__ xout, u16* __restrict__ Bout, u16* __restrict__ Cout,
    float* __restrict__ dtt, int rev)
{
  const int L0 = blockIdx.x*4, b = blockIdx.y, tid = threadIdx.x;
  if (tid < 288){
    const int ch0 = tid*8;
    f32x4 cw4[8];
    #pragma unroll
    for (int j=0;j<8;j++) cw4[j] = *(const f32x4*)&cw[(ch0+j)*4];
    float bias[8];
    {
      f32x4 b0 = *(const f32x4*)&cb[ch0];
      f32x4 b1 = *(const f32x4*)&cb[ch0+4];
      #pragma unroll
      for (int j=0;j<4;j++){ bias[j] = b0[j]; bias[4+j] = b1[j]; }
    }
    u16x8 row[7];
    #pragma unroll
    for (int ri=0; ri<7; ++ri){
      const int ls = L0 - 3 + ri;
      if (ls >= 0){
        const int lsrc = rev ? (LSEQ-1-ls) : ls;
        row[ri] = *(const u16x8*)(zxh + ((size_t)b*LSEQ + lsrc)*NPAD + DINNER + ch0);
      } else {
        #pragma unroll
        for (int j=0;j<8;j++) row[ri][j] = 0;
      }
    }
    #pragma unroll
    for (int i=0;i<4;i++){
      float acc[8];
      #pragma unroll
      for (int j=0;j<8;j++) acc[j] = bias[j];
      #pragma unroll
      for (int k=0;k<4;k++){
        #pragma unroll
        for (int j=0;j<8;j++) acc[j] += cw4[j][k] * bf2f(row[i+k][j]);
      }
      u16x8 o;
      #pragma unroll
      for (int j=0;j<8;j++){
        float sv = acc[j] / (1.f + __expf(-acc[j]));
        o[j] = f2bf(sv);
      }
      const int l = L0 + i;
      if (ch0 < DINNER)
        *(u16x8*)(xout + ((size_t)b*LSEQ + l)*DINNER + ch0) = o;
      else if (ch0 < DINNER+DSTATE)
        *(u16x8*)(Bout + ((size_t)b*LSEQ + l)*DSTATE + (ch0 - DINNER)) = o;
      else
        *(u16x8*)(Cout + ((size_t)b*LSEQ + l)*DSTATE + (ch0 - DINNER - DSTATE)) = o;
    }
  } else {
    const int hh = tid - 288;
    const float dbv = dtb[hh];
    #pragma unroll
    for (int i=0;i<4;i++){
      const int l = L0 + i;
      const int lsrc = rev ? (LSEQ-1-l) : l;
      float raw = bf2f(zxh[((size_t)b*LSEQ + lsrc)*NPAD + DINNER + CONVDIM + hh]) + dbv;
      float dv = (raw > 20.f) ? raw : log1pf(__expf(raw));
      dtt[((size_t)b*NHEADS + hh)*LSEQ + l] = dv;
    }
  }
}

// ---------------- per-chunk inclusive cumsum of dt*A ----------------
__global__ __launch_bounds__(256) void acs_kernel(const float* __restrict__ dtt,
    const float* __restrict__ A_log, float* __restrict__ acs)
{
  const int c = blockIdx.x, hh = blockIdx.y, b = blockIdx.z;
  const int t = threadIdx.x;
  __shared__ float s[CHUNK];
  const float Ah = -__expf(A_log[hh]);
  const size_t base = ((size_t)b*NHEADS + hh)*LSEQ + (size_t)c*CHUNK;
  s[t] = dtt[base + t] * Ah;
  __syncthreads();
  for (int off=1; off<CHUNK; off<<=1){
    float add = (t >= off) ? s[t-off] : 0.f;
    __syncthreads();
    s[t] += add;
    __syncthreads();
  }
  acs[base + t] = s[t];
}

// ---------------- states kernel ----------------
__global__ __launch_bounds__(256) void states_kernel(
    const u16* __restrict__ xb, const u16* __restrict__ Bb,
    const float* __restrict__ dtt, const float* __restrict__ acs,
    u16* __restrict__ states)
{
  const int h = blockIdx.x, c = blockIdx.y, b = blockIdx.z;
  const int tid = threadIdx.x, lane = tid & 63, w = tid >> 6;
  __shared__ float acs_s[CHUNK], dt_s[CHUNK];
  __shared__ u32 xdtTW[64*20];
  __shared__ u32 BsdW[128*20];

  const size_t bhBase = ((size_t)b*NHEADS + h)*LSEQ + (size_t)c*CHUNK;
  acs_s[tid] = acs[bhBase + tid];
  dt_s[tid]  = dtt[bhBase + tid];
  __syncthreads();
  const float acsLast = acs_s[CHUNK-1];

  f32x4 sacc[4][2];
  #pragma unroll
  for (int i=0;i<4;i++){ sacc[i][0] = (f32x4){0,0,0,0}; sacc[i][1] = (f32x4){0,0,0,0}; }

  const int s2 = tid >> 4, q = tid & 15;
  const int g = lane >> 4, r = lane & 15;
  const size_t rowBase = (size_t)b*LSEQ + (size_t)c*CHUNK;
  for (int st8 = 0; st8 < 8; ++st8) {
    const int s0 = st8*32;
    const int sA = s0 + 2*s2, sB = sA + 1;
    u16x4 xA = *(const u16x4*)(xb + (rowBase+sA)*DINNER + h*HEADDIM + 4*q);
    u16x4 xB4 = *(const u16x4*)(xb + (rowBase+sB)*DINNER + h*HEADDIM + 4*q);
    u16x8 bA = *(const u16x8*)(Bb + (rowBase+sA)*DSTATE + 8*q);
    u16x8 bB = *(const u16x8*)(Bb + (rowBase+sB)*DSTATE + 8*q);
    const float dA = dt_s[sA], dB = dt_s[sB];
    const float eA = __expf(acsLast - acs_s[sA]), eB = __expf(acsLast - acs_s[sB]);
    __syncthreads();
    #pragma unroll
    for (int j=0;j<4;j++){
      int p = 4*q + j;
      xdtTW[p*20 + (s2 ^ (((p>>3)&3)<<2))] = pack2(bf2f(xA[j])*dA, bf2f(xB4[j])*dB);
    }
    #pragma unroll
    for (int j=0;j<8;j++){
      int n = 8*q + j;
      BsdW[n*20 + (s2 ^ (((n>>3)&3)<<2))] = pack2(bf2f(bA[j])*eA, bf2f(bB[j])*eB);
    }
    __syncthreads();
    bf16x8 xf[4];
    #pragma unroll
    for (int pt=0;pt<4;pt++){
      int p = pt*16 + r;
      xf[pt] = *(const bf16x8*)&xdtTW[p*20 + 4*(g ^ ((p>>3)&3))];
    }
    #pragma unroll
    for (int nt=0;nt<2;nt++){
      int n = w*32 + nt*16 + r;
      bf16x8 bdf = *(const bf16x8*)&BsdW[n*20 + 4*(g ^ ((n>>3)&3))];
      #pragma unroll
      for (int pt=0;pt<4;pt++) sacc[pt][nt] = mfma16(xf[pt], bdf, sacc[pt][nt]);
    }
  }
  u16* sp = states + (((size_t)b*NCHUNK + c)*NHEADS + h)*(size_t)(HEADDIM*DSTATE);
  #pragma unroll
  for (int pt=0;pt<4;pt++)
    #pragma unroll
    for (int nt=0;nt<2;nt++)
      #pragma unroll
      for (int j=0;j<4;j++)
        sp[(size_t)(pt*16+g*4+j)*DSTATE + w*32+nt*16+r] = f2bf(sacc[pt][nt][j]);
}

// ---------------- inter-chunk state recurrence (512 blocks) ----------------
__global__ __launch_bounds__(256) void recur_kernel(const u16* __restrict__ states,
    const float* __restrict__ acs, u16* __restrict__ prev)
{
  const int bx = blockIdx.x;
  const int seg = bx & 7, bh = bx >> 3;
  const int b = bh >> 5, h = bh & 31;
  const int tid = threadIdx.x;
  float S[4];
  #pragma unroll
  for (int k=0;k<4;k++) S[k] = 0.f;
  for (int c=0;c<NCHUNK;c++){
    const size_t off = (((size_t)b*NCHUNK + c)*NHEADS + h)*(size_t)(HEADDIM*DSTATE)
                     + seg*1024;
    const float dc = __expf(acs[((size_t)b*NHEADS+h)*LSEQ + (size_t)c*CHUNK + CHUNK-1]);
    #pragma unroll
    for (int k=0;k<4;k++){
      const size_t i = off + tid + k*256;
      prev[i] = f2bf(S[k]);
      S[k] = S[k]*dc + bf2f(states[i]);
    }
  }
}

// ---------------- merged Y kernel: Y = Y_diag + exp(Acs)*C*prev^T + D*x ----------------
// Strip-interleaved wave mapping (R10/R17-proven form, 144 VGPR held-caf).
// T5 s_setprio(1) wraps the two pure-MFMA clusters: waves have role diversity
// (strip-skip => different active work per wave per st8) -- the attn-like regime
// where setprio measured +4-7% (m191), unlike lockstep GEMM (null, m190).
__global__ __launch_bounds__(256) void ydiagoff_kernel(
    const u16* __restrict__ xb, const u16* __restrict__ Bb, const u16* __restrict__ Cb,
    const float* __restrict__ dtt, const float* __restrict__ acs,
    const u16* __restrict__ prev, const float* __restrict__ Dp,
    u16* __restrict__ ydir)
{
  const int h = blockIdx.x, c = blockIdx.y, b = blockIdx.z;
  const int tid = threadIdx.x, lane = tid & 63, w = tid >> 6;
  __shared__ float acs_s[CHUNK], dt_s[CHUNK];
  __shared__ u16 Bs[32][136];
  __shared__ u32 xdtTW[64*20];
  __shared__ u16 Ms[4][64][40];

  const size_t bhBase = ((size_t)b*NHEADS + h)*LSEQ + (size_t)c*CHUNK;
  acs_s[tid] = acs[bhBase + tid];
  dt_s[tid]  = dtt[bhBase + tid];
  __syncthreads();

  const int g = lane >> 4, r = lane & 15;
  const size_t rowBase = (size_t)b*LSEQ + (size_t)c*CHUNK;

  bf16x8 caf[4][4];
  const u16* Crow = Cb + rowBase*DSTATE;
  #pragma unroll
  for (int mt=0;mt<4;mt++)
    #pragma unroll
    for (int ks=0;ks<4;ks++)
      caf[mt][ks] = *(const bf16x8*)(Crow + (size_t)(mt*64+w*16+r)*DSTATE + ks*32 + g*8);

  f32x4 yacc[4][4];
  #pragma unroll
  for (int i=0;i<4;i++)
    #pragma unroll
    for (int j=0;j<4;j++) yacc[i][j] = (f32x4){0,0,0,0};

  const int sl = tid >> 3, part = tid & 7;
  const int s2 = tid >> 4, q = tid & 15;
  for (int st8 = 0; st8 < 8; ++st8) {
    const int s0 = st8*32;
    u16x8 v0 = *(const u16x8*)(Bb + (rowBase + s0 + sl)*DSTATE + part*16);
    u16x8 v1 = *(const u16x8*)(Bb + (rowBase + s0 + sl)*DSTATE + part*16 + 8);
    const int sA = s0 + 2*s2, sB = sA + 1;
    u16x4 xA = *(const u16x4*)(xb + (rowBase+sA)*DINNER + h*HEADDIM + 4*q);
    u16x4 xB4 = *(const u16x4*)(xb + (rowBase+sB)*DINNER + h*HEADDIM + 4*q);
    const float dA = dt_s[sA], dB = dt_s[sB];
    __syncthreads();
    *(u16x8*)&Bs[sl][part*16]   = v0;
    *(u16x8*)&Bs[sl][part*16+8] = v1;
    #pragma unroll
    for (int j=0;j<4;j++){
      int p = 4*q + j;
      xdtTW[p*20 + (s2 ^ (((p>>3)&3)<<2))] = pack2(bf2f(xA[j])*dA, bf2f(xB4[j])*dB);
    }
    __syncthreads();
    bf16x8 xf[4];
    #pragma unroll
    for (int pt=0;pt<4;pt++){
      int p = pt*16 + r;
      xf[pt] = *(const bf16x8*)&xdtTW[p*20 + 4*(g ^ ((p>>3)&3))];
    }
    #pragma unroll
    for (int mt=0;mt<4;mt++){
      if (4*mt + w >= 2*st8) {
        f32x4 g20 = (f32x4){0,0,0,0}, g21 = (f32x4){0,0,0,0};
        __builtin_amdgcn_s_setprio(1);
        #pragma unroll
        for (int ks=0;ks<4;ks++){
          bf16x8 bfv0 = *(const bf16x8*)&Bs[r][ks*32+g*8];
          bf16x8 bfv1 = *(const bf16x8*)&Bs[16+r][ks*32+g*8];
          g20 = mfma16(caf[mt][ks], bfv0, g20);
          g21 = mfma16(caf[mt][ks], bfv1, g21);
        }
        __builtin_amdgcn_s_setprio(0);
        #pragma unroll
        for (int j=0;j<4;j++){
          int tl = mt*64 + w*16 + g*4 + j;
          int sg0 = s0 + r;
          int sg1 = s0 + 16 + r;
          float m0 = (sg0 <= tl) ? g20[j]*__expf(acs_s[tl]-acs_s[sg0]) : 0.f;
          float m1 = (sg1 <= tl) ? g21[j]*__expf(acs_s[tl]-acs_s[sg1]) : 0.f;
          Ms[w][mt*16+g*4+j][r]    = f2bf(m0);
          Ms[w][mt*16+g*4+j][16+r] = f2bf(m1);
        }
        bf16x8 mf = *(const bf16x8*)&Ms[w][mt*16+r][g*8];
        __builtin_amdgcn_s_setprio(1);
        #pragma unroll
        for (int pt=0;pt<4;pt++) yacc[mt][pt] = mfma16(mf, xf[pt], yacc[mt][pt]);
        __builtin_amdgcn_s_setprio(0);
      }
    }
  }
  // Y_off: scale caf rows by exp(acs_t), accumulate C*prev^T
  #pragma unroll
  for (int mt=0;mt<4;mt++){
    const float et = __expf(acs_s[mt*64 + w*16 + r]);
    #pragma unroll
    for (int ks=0;ks<4;ks++)
      #pragma unroll
      for (int e=0;e<8;e++)
        caf[mt][ks][e] = (__bf16)((float)caf[mt][ks][e] * et);
  }
  const u16* pv = prev + (((size_t)b*NCHUNK + c)*NHEADS + h)*(size_t)(HEADDIM*DSTATE);
  #pragma unroll
  for (int ks=0;ks<4;ks++){
    bf16x8 pf[4];
    #pragma unroll
    for (int pt=0;pt<4;pt++)
      pf[pt] = *(const bf16x8*)(pv + (size_t)(pt*16+r)*DSTATE + ks*32 + g*8);
    #pragma unroll
    for (int mt=0;mt<4;mt++)
      #pragma unroll
      for (int pt=0;pt<4;pt++) yacc[mt][pt] = mfma16(caf[mt][ks], pf[pt], yacc[mt][pt]);
  }
  const float Dh = Dp[h];
  const u16* xrow = xb + rowBase*DINNER + h*HEADDIM;
  u16* yrow = ydir + rowBase*DINNER + h*HEADDIM;
  #pragma unroll
  for (int mt=0;mt<4;mt++)
    #pragma unroll
    for (int pt=0;pt<4;pt++)
      #pragma unroll
      for (int j=0;j<4;j++){
        int tl = mt*64 + w*16 + g*4 + j;
        int p  = pt*16 + r;
        float xv = bf2f(xrow[(size_t)tl*DINNER + p]);
        yrow[(size_t)tl*DINNER + p] = f2bf(yacc[mt][pt][j] + xv*Dh);
      }
}

// ---------------- gate (silu(z)) + RMSNorm + combine ----------------
__global__ __launch_bounds__(256) void gate_norm_kernel(
    const u16* __restrict__ ydir, const u16* __restrict__ zxh,
    const float* __restrict__ nw, u16* __restrict__ ybufh, int rev)
{
  const int l = blockIdx.x, b = blockIdx.y, tid = threadIdx.x;
  const int lsrc = rev ? (LSEQ-1-l) : l;
  u16x8 zv = *(const u16x8*)(zxh + ((size_t)b*LSEQ + lsrc)*NPAD + tid*8);
  u16x8 yv = *(const u16x8*)(ydir + ((size_t)b*LSEQ + l)*DINNER + tid*8);
  float gg[8]; float ss = 0.f;
  #pragma unroll
  for (int j=0;j<8;j++){
    float z = bf2f(zv[j]);
    float y = bf2f(yv[j]);
    float v = y * (z / (1.f + __expf(-z)));
    gg[j] = v; ss += v*v;
  }
  #pragma unroll
  for (int off=32; off>0; off>>=1) ss += __shfl_xor(ss, off, 64);
  __shared__ float red[4];
  if ((tid&63)==0) red[tid>>6] = ss;
  __syncthreads();
  float tot = red[0]+red[1]+red[2]+red[3];
  float scale = rsqrtf(tot * (1.f/DINNER) + 1e-5f);
  const float* nwp = nw + tid*8;
  u16* hrow = ybufh + ((size_t)b*LSEQ + lsrc)*DINNER + tid*8;
  u16x8 o;
  if (!rev){
    #pragma unroll
    for (int j=0;j<8;j++) o[j] = f2bf(0.5f * gg[j]*scale*nwp[j]);
  } else {
    u16x8 pvv = *(const u16x8*)hrow;
    #pragma unroll
    for (int j=0;j<8;j++) o[j] = f2bf(bf2f(pvv[j]) + 0.5f*gg[j]*scale*nwp[j]);
  }
  *(u16x8*)hrow = o;
}

extern "C" void kernel_launch(void* const* d_in, const int* in_sizes, int n_in,
                              void* d_out, int out_size, void* d_ws, size_t ws_size,
                              hipStream_t stream) {
  const float* u        = (const float*)d_in[0];
  const float* w1       = (const float*)d_in[1];
  const float* conv_w   = (const float*)d_in[2];
  const float* conv_b   = (const float*)d_in[3];
  const float* dt_bias  = (const float*)d_in[4];
  const float* A_log    = (const float*)d_in[5];
  const float* Dp       = (const float*)d_in[6];
  const float* norm_w   = (const float*)d_in[7];
  const float* bconv_w  = (const float*)d_in[8];
  const float* bconv_b  = (const float*)d_in[9];
  const float* bdt_bias = (const float*)d_in[10];
  const float* bA_log   = (const float*)d_in[11];
  const float* bDp      = (const float*)d_in[12];
  const float* bnorm_w  = (const float*)d_in[13];
  const float* wo       = (const float*)d_in[14];
  float* out = (float*)d_out;

  const size_t SZ_ZX  = (size_t)BL*NPAD*2;
  const size_t SZ_UB  = (size_t)BL*DMODEL*2;
  const size_t SZ_W1  = (size_t)NPAD*DMODEL*2;
  const size_t SZ_WO  = (size_t)DMODEL*DINNER*2;
  const size_t SZ_XB  = (size_t)BL*DINNER*2;
  const size_t SZ_BB  = (size_t)BL*DSTATE*2;
  const size_t SZ_DT  = (size_t)BSZ*NHEADS*LSEQ*4;
  const size_t SZ_ST  = (size_t)BSZ*NCHUNK*NHEADS*HEADDIM*DSTATE*2;
  const size_t SZ_YD  = (size_t)BL*DINNER*2;
  const size_t SZ_YH  = (size_t)BL*DINNER*2;
  const size_t NEED = SZ_ZX + SZ_UB + SZ_W1 + SZ_WO + SZ_XB + 2*SZ_BB + 2*SZ_DT
                    + SZ_ST + SZ_YD + SZ_YH;
  if (ws_size < NEED) { sentinel_kernel<<<1,256,0,stream>>>(out); return; }

  char* p = (char*)d_ws;
  u16*   zxh    = (u16*)p;              p += SZ_ZX;
  u16*   ub     = (u16*)p;              p += SZ_UB;
  u16*   states = ub;                   // alias: ub dead after in_proj GEMM
  u16*   w1b    = (u16*)p;              p += SZ_W1;
  u16*   wob    = (u16*)p;              p += SZ_WO;
  u16*   xb     = (u16*)p;              p += SZ_XB;
  u16*   Bb     = (u16*)p;              p += SZ_BB;
  u16*   Cb     = (u16*)p;              p += SZ_BB;
  float* dtt    = (float*)p;            p += SZ_DT;
  float* acs    = (float*)p;            p += SZ_DT;
  u16*   prev   = (u16*)p;              p += SZ_ST;
  u16*   ydir   = (u16*)p;              p += SZ_YD;
  u16*   ybufh  = (u16*)p;              p += SZ_YH;

  cvt3_kernel<<<2048,256,0,stream>>>(u,  ub,  (long)BL*DMODEL,
                                     w1, w1b, (long)DINPROJ*DMODEL, (long)NPAD*DMODEL,
                                     wo, wob, (long)DMODEL*DINNER);

  gemm_bt<1><<<dim3(BL/128, NPAD/128),256,0,stream>>>(ub, w1b, zxh, DMODEL, NPAD);

  for (int dir = 0; dir < 2; ++dir) {
    const float* cwp = dir ? bconv_w  : conv_w;
    const float* cbp = dir ? bconv_b  : conv_b;
    const float* dbp = dir ? bdt_bias : dt_bias;
    const float* alp = dir ? bA_log   : A_log;
    const float* ddp = dir ? bDp      : Dp;
    const float* nwp = dir ? bnorm_w  : norm_w;
    conv_kernel<<<dim3(LSEQ/4,BSZ),320,0,stream>>>(zxh, cwp, cbp, dbp, xb, Bb, Cb, dtt, dir);
    acs_kernel<<<dim3(NCHUNK,NHEADS,BSZ),256,0,stream>>>(dtt, alp, acs);
    states_kernel<<<dim3(NHEADS,NCHUNK,BSZ),256,0,stream>>>(xb, Bb, dtt, acs, states);
    recur_kernel<<<BSZ*NHEADS*8,256,0,stream>>>(states, acs, prev);
    ydiagoff_kernel<<<dim3(NHEADS,NCHUNK,BSZ),256,0,stream>>>(xb, Bb, Cb, dtt, acs, prev, ddp, ydir);
    gate_norm_kernel<<<dim3(LSEQ,BSZ),256,0,stream>>>(ydir, zxh, nwp, ybufh, dir);
  }

  gemm_bt<0><<<dim3(BL/128, DMODEL/128),256,0,stream>>>(ybufh, wob, out, DINNER, DMODEL);
}